// Round 1
// 591.846 us; speedup vs baseline: 1.0024x; 1.0024x over previous
//
#include <hip/hip_runtime.h>
#include <stdint.h>

// dynamic_gcn: B=16, C=32, N=128, T=12, C_OUT=64, fp32 in/out.
// x1[b,i,k,l] = sum_j x[b,i,j,l]*A[b,i,j,k,l]; x2 = same with x1 in place of x;
// out[b,o,k,l] = sum_c W[o,c]*h[b,c,k,l] + bias[o], h = concat(x1,x2) on c.

#define NN 128
#define TT 12
#define KL 1536            // N*T fp32 per j-row
#define KLV 384            // KL/4  (float4)
#define CHUNK4 (NN * KLV)  // float4 per (b,i) chunk of A = 49152 (768 KB)

// Persistent grid: 256 blocks (1/CU) x 768 threads (12 waves/CU); block bx owns
// chunks c0=bx and c1=bx+256 (chunk = (b,i) slice of A, 768 KB). Co-resident
// chunk set is 256 x 768 KB = 192 MB < 256 MB Infinity Cache, so each chunk's
// second (x2) pass re-reads A from L3, and HBM sees A exactly once (~403 MB,
// 64 us floor at 6.3 TB/s).
//
// Phase-interleaved schedule (new this round): the old code ran
//   pass1(c0)[HBM] -> pass2(c0)[L3] -> pass1(c1)[HBM] -> pass2(c1)[L3]
// and since all 256 blocks pace identically, the chip phase-locks: HBM
// saturates while L3 idles, then the reverse -> total = H+L+H+L.
// pass2(c0) and pass1(c1) are independent, so phase B fuses them in one
// j-loop (one L3 load + one HBM load + 8 FMA per thread-iter):
//   A: pass1(c0)[HBM]   B: pass2(c0)[L3] || pass1(c1)[HBM]   C: pass2(c1)[L3]
// -> total = H + max(H,L) + L. Pass-2 walks j in reverse: hottest L3 lines
// (just-streamed tail) first.
__global__ __launch_bounds__(768) void gcn_prop_kernel(
    const float4* __restrict__ A4,
    const float4* __restrict__ x4,
    float4* __restrict__ h4)
{
    __shared__ float4 xs0[KLV];    // x[b,i,:,:] for c0, layout [j*3 + l4] (6 KB)
    __shared__ float4 xs1[KLV];    // x for c1                              (6 KB)
    __shared__ float4 x1s0[KLV];   // combined x1 for c0                    (6 KB)
    __shared__ float4 x1s1[KLV];   // combined x1 for c1                    (6 KB)
    __shared__ float4 ps0[768];    // per-half partials                    (12 KB)
    __shared__ float4 ps1[768];    // second reduction buffer              (12 KB)

    const int t = threadIdx.x;        // 0..767
    const int half = (t >= KLV);      // j-range half: 0 -> j 0..63, 1 -> 64..127
    const int th = t - half * KLV;    // 0..383 : k = th/3, l4 = th%3
    const int la4 = th % 3;
    const int j0 = half * 64;

    const int cid0 = blockIdx.x;          // 0..255  = b*32 + i
    const int cid1 = blockIdx.x + 256;    // 256..511
    const int bb0 = cid0 >> 5, ii0 = cid0 & 31;
    const int bb1 = cid1 >> 5, ii1 = cid1 & 31;
    const float4* Ab0 = A4 + (size_t)cid0 * CHUNK4 + th;
    const float4* Ab1 = A4 + (size_t)cid1 * CHUNK4 + th;

    if (t < KLV) {
        xs0[t] = x4[cid0 * KLV + t];
        xs1[t] = x4[cid1 * KLV + t];
    }
    __syncthreads();

    // ---- phase A: pass1(c0), HBM stream, forward j ----
    float4 acc = make_float4(0.f, 0.f, 0.f, 0.f);
    #pragma unroll 8
    for (int jj = 0; jj < 64; ++jj) {
        const int j = j0 + jj;
        float4 a  = Ab0[j * KLV];      // 1 KB contiguous per wave per j
        float4 xv = xs0[j * 3 + la4];  // 3 distinct addrs/wave: broadcast
        acc.x = fmaf(xv.x, a.x, acc.x);
        acc.y = fmaf(xv.y, a.y, acc.y);
        acc.z = fmaf(xv.z, a.z, acc.z);
        acc.w = fmaf(xv.w, a.w, acc.w);
    }
    ps0[t] = acc;
    __syncthreads();
    if (t < KLV) {
        float4 p0 = ps0[t], p1 = ps0[t + KLV];
        float4 tot = make_float4(p0.x + p1.x, p0.y + p1.y,
                                 p0.z + p1.z, p0.w + p1.w);
        x1s0[t] = tot;
        h4[(size_t)(bb0 * 64 + ii0) * KLV + t] = tot;        // h ch i = x1(c0)
    }
    __syncthreads();

    // ---- phase B: pass2(c0) [L3, reverse j] fused with pass1(c1) [HBM, fwd] ----
    float4 acc2 = make_float4(0.f, 0.f, 0.f, 0.f);   // x2 partial for c0
    float4 acc1 = make_float4(0.f, 0.f, 0.f, 0.f);   // x1 partial for c1
    #pragma unroll 4
    for (int jj = 0; jj < 64; ++jj) {
        const int jr = j0 + 63 - jj;   // c0 pass2: hot L3 tail first
        const int jf = j0 + jj;        // c1 pass1: forward HBM stream
        float4 a2  = Ab0[jr * KLV];    // L3-resident re-read
        float4 x2v = x1s0[jr * 3 + la4];
        float4 a1  = Ab1[jf * KLV];    // HBM stream
        float4 x1v = xs1[jf * 3 + la4];
        acc2.x = fmaf(x2v.x, a2.x, acc2.x);
        acc2.y = fmaf(x2v.y, a2.y, acc2.y);
        acc2.z = fmaf(x2v.z, a2.z, acc2.z);
        acc2.w = fmaf(x2v.w, a2.w, acc2.w);
        acc1.x = fmaf(x1v.x, a1.x, acc1.x);
        acc1.y = fmaf(x1v.y, a1.y, acc1.y);
        acc1.z = fmaf(x1v.z, a1.z, acc1.z);
        acc1.w = fmaf(x1v.w, a1.w, acc1.w);
    }
    ps0[t] = acc2;
    ps1[t] = acc1;
    __syncthreads();
    if (t < KLV) {
        float4 q0 = ps0[t], q1 = ps0[t + KLV];
        float4 tot2 = make_float4(q0.x + q1.x, q0.y + q1.y,
                                  q0.z + q1.z, q0.w + q1.w);
        h4[(size_t)(bb0 * 64 + 32 + ii0) * KLV + t] = tot2;  // h ch 32+i = x2(c0)
        float4 r0 = ps1[t], r1 = ps1[t + KLV];
        float4 tot1 = make_float4(r0.x + r1.x, r0.y + r1.y,
                                  r0.z + r1.z, r0.w + r1.w);
        x1s1[t] = tot1;
        h4[(size_t)(bb1 * 64 + ii1) * KLV + t] = tot1;       // h ch i = x1(c1)
    }
    __syncthreads();

    // ---- phase C: pass2(c1), L3 re-read, reverse j ----
    float4 acc3 = make_float4(0.f, 0.f, 0.f, 0.f);
    #pragma unroll 8
    for (int jj = 0; jj < 64; ++jj) {
        const int j = j0 + 63 - jj;
        float4 a  = Ab1[j * KLV];
        float4 xv = x1s1[j * 3 + la4];
        acc3.x = fmaf(xv.x, a.x, acc3.x);
        acc3.y = fmaf(xv.y, a.y, acc3.y);
        acc3.z = fmaf(xv.z, a.z, acc3.z);
        acc3.w = fmaf(xv.w, a.w, acc3.w);
    }
    ps0[t] = acc3;
    __syncthreads();
    if (t < KLV) {
        float4 p0 = ps0[t], p1 = ps0[t + KLV];
        float4 tot = make_float4(p0.x + p1.x, p0.y + p1.y,
                                 p0.z + p1.z, p0.w + p1.w);
        h4[(size_t)(bb1 * 64 + 32 + ii1) * KLV + t] = tot;   // h ch 32+i = x2(c1)
    }
}

// 1x1 conv over channels: block = (b, o-group of 8). Thread t owns kl=4t..4t+3.
__global__ __launch_bounds__(384) void mix_kernel(
    const float4* __restrict__ h4,
    const float* __restrict__ W,     // [64][64]
    const float* __restrict__ bias,  // [64]
    float4* __restrict__ out4)
{
    __shared__ float wsm[8][64];
    __shared__ float bsm[8];
    const int t = threadIdx.x;
    const int b  = blockIdx.x >> 3;
    const int o0 = (blockIdx.x & 7) * 8;
    {
        const int o = t >> 6, c = t & 63;
        wsm[o][c] = W[(o0 + o) * 64 + c];                    // rows 0..5
    }
    if (t < 128) {
        const int o = 6 + (t >> 6), c = t & 63;
        wsm[o][c] = W[(o0 + o) * 64 + c];                    // rows 6,7
    }
    if (t < 8) bsm[t] = bias[o0 + t];
    __syncthreads();

    float4 acc[8];
    #pragma unroll
    for (int o = 0; o < 8; ++o) {
        const float bv = bsm[o];
        acc[o] = make_float4(bv, bv, bv, bv);
    }
    const float4* hb = h4 + (size_t)b * 64 * KLV + t;
    for (int c = 0; c < 64; ++c) {
        float4 hv = hb[(size_t)c * KLV];     // coalesced across t; L2-resident
        #pragma unroll
        for (int o = 0; o < 8; ++o) {
            const float w = wsm[o][c];       // broadcast: conflict-free
            acc[o].x = fmaf(w, hv.x, acc[o].x);
            acc[o].y = fmaf(w, hv.y, acc[o].y);
            acc[o].z = fmaf(w, hv.z, acc[o].z);
            acc[o].w = fmaf(w, hv.w, acc[o].w);
        }
    }
    #pragma unroll
    for (int o = 0; o < 8; ++o)
        out4[(size_t)(b * 64 + o0 + o) * KLV + t] = acc[o];
}

extern "C" void kernel_launch(void* const* d_in, const int* in_sizes, int n_in,
                              void* d_out, int out_size, void* d_ws, size_t ws_size,
                              hipStream_t stream) {
    const float4* x4 = (const float4*)d_in[0];   // x  [16,32,128,12] fp32
    const float4* A4 = (const float4*)d_in[1];   // A  [16,32,128,128,12] fp32
    const float*  W  = (const float*)d_in[2];    // W  [64,64] fp32
    const float*  bs = (const float*)d_in[3];    // b  [64] fp32
    float4* h4   = (float4*)d_ws;                // h  [16,64,128,12] fp32 = 6 MB
    float4* out4 = (float4*)d_out;               // out[16,64,128,12] fp32

    gcn_prop_kernel<<<dim3(256), dim3(768), 0, stream>>>(A4, x4, h4);
    mix_kernel<<<dim3(128), dim3(384), 0, stream>>>(h4, W, bs, out4);
}